// Round 3
// baseline (190.041 us; speedup 1.0000x reference)
//
#include <hip/hip_runtime.h>
#include <hip/hip_bf16.h>
#include <cstddef>

#define NB  4
#define NC  256
#define NN  4096
#define DQK 32
#define MT  64       // query rows per flash block
#define JT  128      // key tile per iteration
#define NIT (NN / JT)
#define XS2 264      // proj LDS row stride in bf16 ([32 n][256 c] + 8 pad)
#define LOG2E 1.44269504088896340736f

typedef __attribute__((ext_vector_type(8))) short short8;
typedef __attribute__((ext_vector_type(4))) float f32x4;

#define MFMA16(a, b, c) __builtin_amdgcn_mfma_f32_16x16x32_bf16((a), (b), (c), 0, 0, 0)

__device__ inline unsigned pk2bf(float a, float b) {
  __hip_bfloat162 h = __float22bfloat162_rn(make_float2(a, b));
  unsigned u;
  __builtin_memcpy(&u, &h, 4);
  return u;
}

// lgkm-only barrier: LDS ops visible, vm prefetches stay in flight.
__device__ inline void bar_lgkm() {
  asm volatile("s_waitcnt lgkmcnt(0)" ::: "memory");
  __builtin_amdgcn_s_barrier();
}

// ---- W convert: [Wq(32);Wk(32);Wv(256)] f32 -> W16[320][256] bf16 ----
// Wq rows pre-scaled by log2(e) so flash uses exp2 directly.
__global__ __launch_bounds__(256) void wcvt_kernel(
    const float* __restrict__ Wq, const float* __restrict__ Wk,
    const float* __restrict__ Wv, __hip_bfloat16* __restrict__ W16) {
  const int id4 = (blockIdx.x * 256 + threadIdx.x) * 4;   // 80 blocks -> 81920
  const int row = id4 >> 8, col = id4 & 255;
  const float* src = (row < 32) ? Wq + row * 256
                   : (row < 64) ? Wk + (row - 32) * 256
                                : Wv + (row - 64) * 256;
  float4 vv = *(const float4*)(src + col);
  if (row < 32) { vv.x *= LOG2E; vv.y *= LOG2E; vv.z *= LOG2E; vv.w *= LOG2E; }
  *(uint2*)(W16 + id4) = make_uint2(pk2bf(vv.x, vv.y), pk2bf(vv.z, vv.w));
}

// ---- fused proj: stage x-slice [256 c][32 n] to LDS ONCE (as [n][c] bf16),
// ---- one barrier, then 80 MFMAs flat (no in-loop syncs at all).
__global__ __launch_bounds__(256) void proj_kernel(
    const float* __restrict__ x, const __hip_bfloat16* __restrict__ W16,
    const float* __restrict__ bq, const float* __restrict__ bk,
    const float* __restrict__ bv, __hip_bfloat16* __restrict__ q,
    __hip_bfloat16* __restrict__ kT, __hip_bfloat16* __restrict__ v) {
  __shared__ __hip_bfloat16 Xs[32 * XS2];   // 16896 B
  const int t = threadIdx.x;
  const int b = blockIdx.y, n0 = blockIdx.x * 32;
  const int w = __builtin_amdgcn_readfirstlane(t >> 6);   // wave: o rows [w*80, w*80+80)
  const int ln = t & 15, quad = (t & 63) >> 4;
  const int sn = t & 31, scg = t >> 5;   // staging: n lane, c-group (8 groups of 8)

  // ---- stage: thread (sn,scg) loads c = g*64 + scg*8 + i, n = n0+sn ----
  const float* xsrc = x + (size_t)b * NC * NN + n0 + sn;
  float xr[4][8];
#pragma unroll
  for (int g = 0; g < 4; ++g)
#pragma unroll
    for (int i = 0; i < 8; ++i)
      xr[g][i] = xsrc[(size_t)(g * 64 + scg * 8 + i) * NN];
#pragma unroll
  for (int g = 0; g < 4; ++g) {
    uint4 pw;
    pw.x = pk2bf(xr[g][0], xr[g][1]);
    pw.y = pk2bf(xr[g][2], xr[g][3]);
    pw.z = pk2bf(xr[g][4], xr[g][5]);
    pw.w = pk2bf(xr[g][6], xr[g][7]);
    *(uint4*)&Xs[sn * XS2 + g * 64 + scg * 8] = pw;
  }
  bar_lgkm();   // the only barrier

  f32x4 zero4 = {0.f, 0.f, 0.f, 0.f};
  f32x4 acc[5][2];
#pragma unroll
  for (int i = 0; i < 5; ++i)
#pragma unroll
    for (int j = 0; j < 2; ++j) acc[i][j] = zero4;

#pragma unroll
  for (int k0 = 0; k0 < NC; k0 += 32) {
    short8 af[5], bfr[2];
#pragma unroll
    for (int ot = 0; ot < 5; ++ot)
      af[ot] = *(const short8*)(W16 + (size_t)(w * 80 + ot * 16 + ln) * NC + k0 + quad * 8);
#pragma unroll
    for (int nt = 0; nt < 2; ++nt)
      bfr[nt] = *(const short8*)&Xs[(nt * 16 + ln) * XS2 + k0 + quad * 8];
#pragma unroll
    for (int ot = 0; ot < 5; ++ot)
#pragma unroll
      for (int nt = 0; nt < 2; ++nt)
        acc[ot][nt] = MFMA16(af[ot], bfr[nt], acc[ot][nt]);
  }

  // epilogue: rows [0,32)->q[b][n][o] (log2e-scaled), [32,64)->kT, [64,320)->v
#pragma unroll
  for (int ot = 0; ot < 5; ++ot) {
    const int gbase = w * 80 + ot * 16;    // wave-uniform
    if (gbase < 32) {
#pragma unroll
      for (int nt = 0; nt < 2; ++nt)
#pragma unroll
        for (int r = 0; r < 4; ++r) {
          const int row = gbase + quad * 4 + r;
          q[((size_t)b * NN + n0 + nt * 16 + ln) * DQK + row] =
              __hip_bfloat16(acc[ot][nt][r] + bq[row] * LOG2E);
        }
    } else if (gbase < 64) {
#pragma unroll
      for (int nt = 0; nt < 2; ++nt)
#pragma unroll
        for (int r = 0; r < 4; ++r) {
          const int row = gbase - 32 + quad * 4 + r;
          kT[((size_t)b * NN + n0 + nt * 16 + ln) * DQK + row] =
              __hip_bfloat16(acc[ot][nt][r] + bk[row]);
        }
    } else {
#pragma unroll
      for (int nt = 0; nt < 2; ++nt)
#pragma unroll
        for (int r = 0; r < 4; ++r) {
          const int c = gbase - 64 + quad * 4 + r;
          v[((size_t)b * NC + c) * NN + n0 + nt * 16 + ln] =
              __hip_bfloat16(acc[ot][nt][r] + bv[c]);
        }
    }
  }
}

// ---- wave-specialized flash, c-split 2 blocks/CU: blocks bi and bi+256 share
// ---- tile (b, m0); each runs the full producer (P duplicated, +11% MFMA) but
// ---- consumers cover half the channels -> 16 waves/CU fill issue stalls.
__global__ __launch_bounds__(512, 4) void flash_kernel(
    const __hip_bfloat16* __restrict__ q, const __hip_bfloat16* __restrict__ kt,
    const __hip_bfloat16* __restrict__ v, const float* __restrict__ x,
    const float* __restrict__ gamma, float* __restrict__ out) {
  // P rows: 64 m x 256 B (128 j), byte-in-row XOR'd with (m&7)<<4
  __shared__ __align__(16) __hip_bfloat16 Ps[2][MT * JT];   // 32768 B
  __shared__ float lrow[MT];

  const int t     = threadIdx.x;
  const int bi    = blockIdx.x;
  const int tile  = bi & 255;      // bi and bi+256 share a tile, same XCD (bi%8)
  const int phalf = bi >> 8;       // c-half: 0 -> [0,128), 1 -> [128,256)
  // XCD swizzle: XCD pair {2b,2b+1} serves batch b -> V slice ~2 MB in L2
  const int b  = (tile & 7) >> 1;
  const int m0 = (((tile & 1) * 32) + (tile >> 3)) * MT;

  const int w    = __builtin_amdgcn_readfirstlane(t >> 6);   // 0..7
  const int ln   = t & 15;
  const int quad = (t & 63) >> 4;

  const __hip_bfloat16* kb_base = kt + (size_t)b * NN * DQK;
  const __hip_bfloat16* v_base  = v + (size_t)b * NC * NN;

  if (w < 4) {
    // ------- producer: m = m0 + w*16 + ln (lane-local row), 8 j-tiles/iter -------
    const short8 qa =
        *(const short8*)(q + ((size_t)b * NN + m0 + w * 16 + ln) * DQK + quad * 8);
    float lreg = 0.f;
    const f32x4 zero4 = {0.f, 0.f, 0.f, 0.f};
    short8 kb[8];
#pragma unroll
    for (int jt = 0; jt < 8; ++jt)
      kb[jt] = *(const short8*)(kb_base + (size_t)(jt * 16 + ln) * DQK + quad * 8);

    const int m = w * 16 + ln;

    for (int it = 0; it < NIT; ++it) {
      // S^T strip: mfma(K, Q) -> lane holds S[m=ln][j = jt*16 + quad*4 + r]
      f32x4 st[8];
      __builtin_amdgcn_s_setprio(1);
#pragma unroll
      for (int jt = 0; jt < 8; ++jt) st[jt] = MFMA16(kb[jt], qa, zero4);
      __builtin_amdgcn_s_setprio(0);

      // prefetch next K (stays in flight across the lgkm barrier)
      if (it + 1 < NIT) {
        const int jn = (it + 1) * JT;
#pragma unroll
        for (int jt = 0; jt < 8; ++jt)
          kb[jt] = *(const short8*)(kb_base + (size_t)(jn + jt * 16 + ln) * DQK + quad * 8);
      }

      // P = exp2(S); packed b64 writes: j block [jt*16+quad*4, +4) for row m
      char* pbase = (char*)&Ps[it & 1][0] + m * (JT * 2);
#pragma unroll
      for (int jt = 0; jt < 8; ++jt) {
        const float e0 = exp2f(st[jt][0]), e1 = exp2f(st[jt][1]);
        const float e2 = exp2f(st[jt][2]), e3 = exp2f(st[jt][3]);
        lreg += (e0 + e1) + (e2 + e3);
        *(uint2*)(pbase + ((jt * 32 + quad * 8) ^ ((m & 7) << 4))) =
            make_uint2(pk2bf(e0, e1), pk2bf(e2, e3));
      }
      bar_lgkm();   // barrier #(it+1)
    }
    // reduce l over the 4 quads (each held a disjoint j subset for this m)
    lreg += __shfl_xor(lreg, 16);
    lreg += __shfl_xor(lreg, 32);
    if (quad == 0) lrow[w * 16 + ln] = lreg;
    bar_lgkm();     // barrier #(NIT+1)
  } else {
    // ------- consumer: channels [c0, c0+32), one iter behind -------
    const int c0 = phalf * 128 + (w - 4) * 32;
    const f32x4 zero4 = {0.f, 0.f, 0.f, 0.f};
    f32x4 acc[2][4];   // rows c = c0+ct*16+quad*4+r, cols m = mt*16+ln
#pragma unroll
    for (int ct = 0; ct < 2; ++ct)
#pragma unroll
      for (int mt = 0; mt < 4; ++mt) acc[ct][mt] = zero4;

    short8 va[2][4];   // [ct][ks], K elems n = ks*32 + quad*8
#pragma unroll
    for (int ct = 0; ct < 2; ++ct)
#pragma unroll
      for (int ks = 0; ks < 4; ++ks)
        va[ct][ks] = *(const short8*)(v_base +
            (size_t)(c0 + ct * 16 + ln) * NN + ks * 32 + quad * 8);
    bar_lgkm();   // barrier #1 (aligns with producer it=0)

    for (int it = 1; it < NIT; ++it) {
      const char* pbase = (const char*)&Ps[(it - 1) & 1][0];
      const int j0 = it * JT;
#pragma unroll
      for (int ks = 0; ks < 4; ++ks) {
        short8 pb[4];
#pragma unroll
        for (int mt = 0; mt < 4; ++mt)
          pb[mt] = *(const short8*)(pbase + (mt * 16 + ln) * (JT * 2) +
                                    ((ks * 64 + quad * 16) ^ ((ln & 7) << 4)));
        __builtin_amdgcn_s_setprio(1);
#pragma unroll
        for (int ct = 0; ct < 2; ++ct)
#pragma unroll
          for (int mt = 0; mt < 4; ++mt)
            acc[ct][mt] = MFMA16(va[ct][ks], pb[mt], acc[ct][mt]);
        __builtin_amdgcn_s_setprio(0);
        // reload this ks-slice of V for the next iteration (issue-early)
#pragma unroll
        for (int ct = 0; ct < 2; ++ct)
          va[ct][ks] = *(const short8*)(v_base +
              (size_t)(c0 + ct * 16 + ln) * NN + j0 + ks * 32 + quad * 8);
      }
      bar_lgkm();   // barrier #(it+1)
    }

    // final PV for tile NIT-1
    {
      const char* pbase = (const char*)&Ps[(NIT - 1) & 1][0];
#pragma unroll
      for (int ks = 0; ks < 4; ++ks) {
        short8 pb[4];
#pragma unroll
        for (int mt = 0; mt < 4; ++mt)
          pb[mt] = *(const short8*)(pbase + (mt * 16 + ln) * (JT * 2) +
                                    ((ks * 64 + quad * 16) ^ ((ln & 7) << 4)));
        __builtin_amdgcn_s_setprio(1);
#pragma unroll
        for (int ct = 0; ct < 2; ++ct)
#pragma unroll
          for (int mt = 0; mt < 4; ++mt)
            acc[ct][mt] = MFMA16(va[ct][ks], pb[mt], acc[ct][mt]);
        __builtin_amdgcn_s_setprio(0);
      }
    }
    bar_lgkm();     // barrier #(NIT+1): lrow visible

    // epilogue: out[b][c][m] = gamma*(O'/l) + x
    const float g0 = gamma[0];
    float li[4];
#pragma unroll
    for (int mt = 0; mt < 4; ++mt) li[mt] = 1.f / lrow[mt * 16 + ln];
#pragma unroll
    for (int ct = 0; ct < 2; ++ct)
#pragma unroll
      for (int r = 0; r < 4; ++r) {
        const int c = c0 + ct * 16 + quad * 4 + r;
        const float* xr = x + ((size_t)b * NC + c) * NN + m0;
        float* orow = out + ((size_t)b * NC + c) * NN + m0;
#pragma unroll
        for (int mt = 0; mt < 4; ++mt) {
          const int m = mt * 16 + ln;
          orow[m] = g0 * (acc[ct][mt][r] * li[mt]) + xr[m];
        }
      }
  }
}

extern "C" void kernel_launch(void* const* d_in, const int* in_sizes, int n_in,
                              void* d_out, int out_size, void* d_ws, size_t ws_size,
                              hipStream_t stream) {
  const float* x     = (const float*)d_in[0];
  const float* Wq    = (const float*)d_in[1];
  const float* bq    = (const float*)d_in[2];
  const float* Wk    = (const float*)d_in[3];
  const float* bk    = (const float*)d_in[4];
  const float* Wv    = (const float*)d_in[5];
  const float* bv    = (const float*)d_in[6];
  const float* gamma = (const float*)d_in[7];
  float* out = (float*)d_out;

  char* wsp = (char*)d_ws;
  __hip_bfloat16* W16 = (__hip_bfloat16*)wsp;  wsp += (size_t)320 * NC * 2;
  __hip_bfloat16* q   = (__hip_bfloat16*)wsp;  wsp += (size_t)NB * NN * DQK * 2;
  __hip_bfloat16* kT  = (__hip_bfloat16*)wsp;  wsp += (size_t)NB * NN * DQK * 2;
  __hip_bfloat16* v   = (__hip_bfloat16*)wsp;  // + 8.4 MB => ~10.6 MB total

  wcvt_kernel<<<dim3(80), dim3(256), 0, stream>>>(Wq, Wk, Wv, W16);
  proj_kernel<<<dim3(NN / 32, NB), dim3(256), 0, stream>>>(x, W16, bq, bk, bv, q, kT, v);
  flash_kernel<<<dim3(NB * NN / MT * 2), dim3(512), 0, stream>>>(q, kT, v, x, gamma, out);
}

// Round 7
// 171.653 us; speedup vs baseline: 1.1071x; 1.1071x over previous
//
#include <hip/hip_runtime.h>
#include <hip/hip_bf16.h>
#include <cstddef>

#define NB  4
#define NC  256
#define NN  4096
#define DQK 32
#define MT  64       // query rows per flash block
#define JT  128      // key tile per iteration
#define NIT (NN / JT)
#define XS2 264      // proj LDS row stride in bf16 ([32 n][256 c] + 8 pad)

typedef __attribute__((ext_vector_type(8))) short short8;
typedef __attribute__((ext_vector_type(4))) float f32x4;

#define MFMA16(a, b, c) __builtin_amdgcn_mfma_f32_16x16x32_bf16((a), (b), (c), 0, 0, 0)

__device__ inline unsigned pk2bf(float a, float b) {
  __hip_bfloat162 h = __float22bfloat162_rn(make_float2(a, b));
  unsigned u;
  __builtin_memcpy(&u, &h, 4);
  return u;
}

// lgkm-only barrier, fenced on BOTH sides: s_barrier is IntrNoMem, so without
// the trailing clobber LLVM may hoist post-barrier LDS reads above it (the
// race that broke round 5). vm prefetches stay in flight (no vmcnt drain).
__device__ inline void bar_lgkm() {
  asm volatile("s_waitcnt lgkmcnt(0)" ::: "memory");
  __builtin_amdgcn_s_barrier();
  asm volatile("" ::: "memory");
}

// ---- W convert: [Wq(32);Wk(32);Wv(256)] f32 -> W16[320][256] bf16 ----
__global__ __launch_bounds__(256) void wcvt_kernel(
    const float* __restrict__ Wq, const float* __restrict__ Wk,
    const float* __restrict__ Wv, __hip_bfloat16* __restrict__ W16) {
  const int id4 = (blockIdx.x * 256 + threadIdx.x) * 4;   // 80 blocks -> 81920
  const int row = id4 >> 8, col = id4 & 255;
  const float* src = (row < 32) ? Wq + row * 256
                   : (row < 64) ? Wk + (row - 32) * 256
                                : Wv + (row - 64) * 256;
  float4 vv = *(const float4*)(src + col);
  *(uint2*)(W16 + id4) = make_uint2(pk2bf(vv.x, vv.y), pk2bf(vv.z, vv.w));
}

// ---- fused proj: stage x-slice [256 c][32 n] to LDS ONCE (as [n][c] bf16),
// ---- one barrier, then 80 MFMAs flat (no in-loop syncs at all).
__global__ __launch_bounds__(256) void proj_kernel(
    const float* __restrict__ x, const __hip_bfloat16* __restrict__ W16,
    const float* __restrict__ bq, const float* __restrict__ bk,
    const float* __restrict__ bv, __hip_bfloat16* __restrict__ q,
    __hip_bfloat16* __restrict__ kT, __hip_bfloat16* __restrict__ v) {
  __shared__ __hip_bfloat16 Xs[32 * XS2];   // 16896 B
  const int t = threadIdx.x;
  const int b = blockIdx.y, n0 = blockIdx.x * 32;
  const int w = __builtin_amdgcn_readfirstlane(t >> 6);   // wave: o rows [w*80, w*80+80)
  const int ln = t & 15, quad = (t & 63) >> 4;
  const int sn = t & 31, scg = t >> 5;   // staging: n lane, c-group (8 groups of 8)

  // ---- stage: thread (sn,scg) loads c = g*64 + scg*8 + i, n = n0+sn ----
  const float* xsrc = x + (size_t)b * NC * NN + n0 + sn;
  float xr[4][8];
#pragma unroll
  for (int g = 0; g < 4; ++g)
#pragma unroll
    for (int i = 0; i < 8; ++i)
      xr[g][i] = xsrc[(size_t)(g * 64 + scg * 8 + i) * NN];
#pragma unroll
  for (int g = 0; g < 4; ++g) {
    uint4 pw;
    pw.x = pk2bf(xr[g][0], xr[g][1]);
    pw.y = pk2bf(xr[g][2], xr[g][3]);
    pw.z = pk2bf(xr[g][4], xr[g][5]);
    pw.w = pk2bf(xr[g][6], xr[g][7]);
    *(uint4*)&Xs[sn * XS2 + g * 64 + scg * 8] = pw;
  }
  bar_lgkm();   // the only barrier

  f32x4 zero4 = {0.f, 0.f, 0.f, 0.f};
  f32x4 acc[5][2];
#pragma unroll
  for (int i = 0; i < 5; ++i)
#pragma unroll
    for (int j = 0; j < 2; ++j) acc[i][j] = zero4;

#pragma unroll
  for (int k0 = 0; k0 < NC; k0 += 32) {
    short8 af[5], bfr[2];
#pragma unroll
    for (int ot = 0; ot < 5; ++ot)
      af[ot] = *(const short8*)(W16 + (size_t)(w * 80 + ot * 16 + ln) * NC + k0 + quad * 8);
#pragma unroll
    for (int nt = 0; nt < 2; ++nt)
      bfr[nt] = *(const short8*)&Xs[(nt * 16 + ln) * XS2 + k0 + quad * 8];
#pragma unroll
    for (int ot = 0; ot < 5; ++ot)
#pragma unroll
      for (int nt = 0; nt < 2; ++nt)
        acc[ot][nt] = MFMA16(af[ot], bfr[nt], acc[ot][nt]);
  }

  // epilogue: rows [0,32)->q[b][n][o], [32,64)->kT, [64,320)->v
#pragma unroll
  for (int ot = 0; ot < 5; ++ot) {
    const int gbase = w * 80 + ot * 16;    // wave-uniform
    if (gbase < 32) {
#pragma unroll
      for (int nt = 0; nt < 2; ++nt)
#pragma unroll
        for (int r = 0; r < 4; ++r) {
          const int row = gbase + quad * 4 + r;
          q[((size_t)b * NN + n0 + nt * 16 + ln) * DQK + row] =
              __hip_bfloat16(acc[ot][nt][r] + bq[row]);
        }
    } else if (gbase < 64) {
#pragma unroll
      for (int nt = 0; nt < 2; ++nt)
#pragma unroll
        for (int r = 0; r < 4; ++r) {
          const int row = gbase - 32 + quad * 4 + r;
          kT[((size_t)b * NN + n0 + nt * 16 + ln) * DQK + row] =
              __hip_bfloat16(acc[ot][nt][r] + bk[row]);
        }
    } else {
#pragma unroll
      for (int nt = 0; nt < 2; ++nt)
#pragma unroll
        for (int r = 0; r < 4; ++r) {
          const int c = gbase - 64 + quad * 4 + r;
          v[((size_t)b * NC + c) * NN + n0 + nt * 16 + ln] =
              __hip_bfloat16(acc[ot][nt][r] + bv[c]);
        }
    }
  }
}

// ---- wave-specialized flash (round-2 structure + fenced barriers): waves 0-3
// ---- produce P = exp(S) via swapped QK^T (__expf: inlined v_mul+v_exp, the
// ---- hazard-safe fast path), waves 4-7 consume (PV), one iter behind,
// ---- double-buffered swizzled P, lgkm-only fenced barriers.
__global__ __launch_bounds__(512, 2) void flash_kernel(
    const __hip_bfloat16* __restrict__ q, const __hip_bfloat16* __restrict__ kt,
    const __hip_bfloat16* __restrict__ v, const float* __restrict__ x,
    const float* __restrict__ gamma, float* __restrict__ out) {
  // P rows: 64 m x 256 B (128 j), byte-in-row XOR'd with (m&7)<<4
  __shared__ __align__(16) __hip_bfloat16 Ps[2][MT * JT];   // 32768 B
  __shared__ float lrow[MT];

  const int t  = threadIdx.x;
  const int bi = blockIdx.x;
  // XCD swizzle: XCD pair {2b,2b+1} serves batch b -> V slice ~2 MB in L2
  const int b  = (bi & 7) >> 1;
  const int m0 = (((bi & 1) * 32) + (bi >> 3)) * MT;

  const int w    = __builtin_amdgcn_readfirstlane(t >> 6);   // 0..7
  const int ln   = t & 15;
  const int quad = (t & 63) >> 4;

  const __hip_bfloat16* kb_base = kt + (size_t)b * NN * DQK;
  const __hip_bfloat16* v_base  = v + (size_t)b * NC * NN;

  if (w < 4) {
    // ------- producer: m = m0 + w*16 + ln (lane-local row), 8 j-tiles/iter -------
    const short8 qa =
        *(const short8*)(q + ((size_t)b * NN + m0 + w * 16 + ln) * DQK + quad * 8);
    float lreg = 0.f;
    const f32x4 zero4 = {0.f, 0.f, 0.f, 0.f};
    short8 kb[8];
#pragma unroll
    for (int jt = 0; jt < 8; ++jt)
      kb[jt] = *(const short8*)(kb_base + (size_t)(jt * 16 + ln) * DQK + quad * 8);

    const int m = w * 16 + ln;

    for (int it = 0; it < NIT; ++it) {
      // S^T strip: mfma(K, Q) -> lane holds S[m=ln][j = jt*16 + quad*4 + r]
      f32x4 st[8];
      __builtin_amdgcn_s_setprio(1);
#pragma unroll
      for (int jt = 0; jt < 8; ++jt) st[jt] = MFMA16(kb[jt], qa, zero4);
      __builtin_amdgcn_s_setprio(0);

      // prefetch next K (stays in flight across the lgkm barrier)
      if (it + 1 < NIT) {
        const int jn = (it + 1) * JT;
#pragma unroll
        for (int jt = 0; jt < 8; ++jt)
          kb[jt] = *(const short8*)(kb_base + (size_t)(jn + jt * 16 + ln) * DQK + quad * 8);
      }

      // P = exp(S); packed b64 writes: j block [jt*16+quad*4, +4) for row m
      char* pbase = (char*)&Ps[it & 1][0] + m * (JT * 2);
#pragma unroll
      for (int jt = 0; jt < 8; ++jt) {
        const float e0 = __expf(st[jt][0]), e1 = __expf(st[jt][1]);
        const float e2 = __expf(st[jt][2]), e3 = __expf(st[jt][3]);
        lreg += (e0 + e1) + (e2 + e3);
        *(uint2*)(pbase + ((jt * 32 + quad * 8) ^ ((m & 7) << 4))) =
            make_uint2(pk2bf(e0, e1), pk2bf(e2, e3));
      }
      bar_lgkm();   // barrier #(it+1)
    }
    // reduce l over the 4 quads (each held a disjoint j subset for this m)
    lreg += __shfl_xor(lreg, 16);
    lreg += __shfl_xor(lreg, 32);
    if (quad == 0) lrow[w * 16 + ln] = lreg;
    bar_lgkm();     // barrier #(NIT+1)
  } else {
    // ------- consumer: channels [c0, c0+64), one iter behind -------
    const int c0 = (w - 4) * 64;
    const f32x4 zero4 = {0.f, 0.f, 0.f, 0.f};
    f32x4 acc[4][4];   // rows c = c0+ct*16+quad*4+r, cols m = mt*16+ln
#pragma unroll
    for (int ct = 0; ct < 4; ++ct)
#pragma unroll
      for (int mt = 0; mt < 4; ++mt) acc[ct][mt] = zero4;

    short8 va[4][4];   // [ct][ks], K elems n = ks*32 + quad*8
#pragma unroll
    for (int ct = 0; ct < 4; ++ct)
#pragma unroll
      for (int ks = 0; ks < 4; ++ks)
        va[ct][ks] = *(const short8*)(v_base +
            (size_t)(c0 + ct * 16 + ln) * NN + ks * 32 + quad * 8);
    bar_lgkm();   // barrier #1 (aligns with producer it=0)

    for (int it = 1; it < NIT; ++it) {
      const char* pbase = (const char*)&Ps[(it - 1) & 1][0];
      const int j0 = it * JT;
#pragma unroll
      for (int ks = 0; ks < 4; ++ks) {
        short8 pb[4];
#pragma unroll
        for (int mt = 0; mt < 4; ++mt)
          pb[mt] = *(const short8*)(pbase + (mt * 16 + ln) * (JT * 2) +
                                    ((ks * 64 + quad * 16) ^ ((ln & 7) << 4)));
        __builtin_amdgcn_s_setprio(1);
#pragma unroll
        for (int ct = 0; ct < 4; ++ct)
#pragma unroll
          for (int mt = 0; mt < 4; ++mt)
            acc[ct][mt] = MFMA16(va[ct][ks], pb[mt], acc[ct][mt]);
        __builtin_amdgcn_s_setprio(0);
        // reload this ks-slice of V for the next iteration (issue-early)
#pragma unroll
        for (int ct = 0; ct < 4; ++ct)
          va[ct][ks] = *(const short8*)(v_base +
              (size_t)(c0 + ct * 16 + ln) * NN + j0 + ks * 32 + quad * 8);
      }
      bar_lgkm();   // barrier #(it+1)
    }

    // final PV for tile NIT-1
    {
      const char* pbase = (const char*)&Ps[(NIT - 1) & 1][0];
#pragma unroll
      for (int ks = 0; ks < 4; ++ks) {
        short8 pb[4];
#pragma unroll
        for (int mt = 0; mt < 4; ++mt)
          pb[mt] = *(const short8*)(pbase + (mt * 16 + ln) * (JT * 2) +
                                    ((ks * 64 + quad * 16) ^ ((ln & 7) << 4)));
        __builtin_amdgcn_s_setprio(1);
#pragma unroll
        for (int ct = 0; ct < 4; ++ct)
#pragma unroll
          for (int mt = 0; mt < 4; ++mt)
            acc[ct][mt] = MFMA16(va[ct][ks], pb[mt], acc[ct][mt]);
        __builtin_amdgcn_s_setprio(0);
      }
    }
    bar_lgkm();     // barrier #(NIT+1): lrow visible

    // epilogue: out[b][c][m] = gamma*(O'/l) + x
    const float g0 = gamma[0];
    float li[4];
#pragma unroll
    for (int mt = 0; mt < 4; ++mt) li[mt] = 1.f / lrow[mt * 16 + ln];
#pragma unroll
    for (int ct = 0; ct < 4; ++ct)
#pragma unroll
      for (int r = 0; r < 4; ++r) {
        const int c = c0 + ct * 16 + quad * 4 + r;
        const float* xr = x + ((size_t)b * NC + c) * NN + m0;
        float* orow = out + ((size_t)b * NC + c) * NN + m0;
#pragma unroll
        for (int mt = 0; mt < 4; ++mt) {
          const int m = mt * 16 + ln;
          orow[m] = g0 * (acc[ct][mt][r] * li[mt]) + xr[m];
        }
      }
  }
}

extern "C" void kernel_launch(void* const* d_in, const int* in_sizes, int n_in,
                              void* d_out, int out_size, void* d_ws, size_t ws_size,
                              hipStream_t stream) {
  const float* x     = (const float*)d_in[0];
  const float* Wq    = (const float*)d_in[1];
  const float* bq    = (const float*)d_in[2];
  const float* Wk    = (const float*)d_in[3];
  const float* bk    = (const float*)d_in[4];
  const float* Wv    = (const float*)d_in[5];
  const float* bv    = (const float*)d_in[6];
  const float* gamma = (const float*)d_in[7];
  float* out = (float*)d_out;

  char* wsp = (char*)d_ws;
  __hip_bfloat16* W16 = (__hip_bfloat16*)wsp;  wsp += (size_t)320 * NC * 2;
  __hip_bfloat16* q   = (__hip_bfloat16*)wsp;  wsp += (size_t)NB * NN * DQK * 2;
  __hip_bfloat16* kT  = (__hip_bfloat16*)wsp;  wsp += (size_t)NB * NN * DQK * 2;
  __hip_bfloat16* v   = (__hip_bfloat16*)wsp;  // + 8.4 MB => ~10.6 MB total

  wcvt_kernel<<<dim3(80), dim3(256), 0, stream>>>(Wq, Wk, Wv, W16);
  proj_kernel<<<dim3(NN / 32, NB), dim3(256), 0, stream>>>(x, W16, bq, bk, bv, q, kT, v);
  flash_kernel<<<dim3(NB * NN / MT), dim3(512), 0, stream>>>(q, kT, v, x, gamma, out);
}

// Round 8
// 167.117 us; speedup vs baseline: 1.1372x; 1.0271x over previous
//
#include <hip/hip_runtime.h>
#include <hip/hip_bf16.h>
#include <cstddef>

#define NB  4
#define NC  256
#define NN  4096
#define DQK 32
#define MT  64       // query rows per flash block
#define JT  64       // key tile per iteration
#define NIT (NN / JT)
#define XS2 264      // proj LDS row stride in bf16 ([32 n][256 c] + 8 pad)

typedef __attribute__((ext_vector_type(8))) short short8;
typedef __attribute__((ext_vector_type(4))) float f32x4;

#define MFMA16(a, b, c) __builtin_amdgcn_mfma_f32_16x16x32_bf16((a), (b), (c), 0, 0, 0)

__device__ inline unsigned pk2bf(float a, float b) {
  __hip_bfloat162 h = __float22bfloat162_rn(make_float2(a, b));
  unsigned u;
  __builtin_memcpy(&u, &h, 4);
  return u;
}

// async global->LDS, 16B per lane; LDS dest = uniform base + lane*16 (linear),
// global src is per-lane (pre-swizzled to realize the XOR'd LDS layout).
__device__ inline void gl16(const void* g, void* s) {
  __builtin_amdgcn_global_load_lds(
      (const __attribute__((address_space(1))) void*)g,
      (__attribute__((address_space(3))) void*)s, 16, 0, 0);
}

// ---- W convert: [Wq(32);Wk(32);Wv(256)] f32 -> W16[320][256] bf16 ----
__global__ __launch_bounds__(256) void wcvt_kernel(
    const float* __restrict__ Wq, const float* __restrict__ Wk,
    const float* __restrict__ Wv, __hip_bfloat16* __restrict__ W16) {
  const int id4 = (blockIdx.x * 256 + threadIdx.x) * 4;   // 80 blocks -> 81920
  const int row = id4 >> 8, col = id4 & 255;
  const float* src = (row < 32) ? Wq + row * 256
                   : (row < 64) ? Wk + (row - 32) * 256
                                : Wv + (row - 64) * 256;
  float4 vv = *(const float4*)(src + col);
  *(uint2*)(W16 + id4) = make_uint2(pk2bf(vv.x, vv.y), pk2bf(vv.z, vv.w));
}

// ---- fused proj: stage x-slice [256 c][32 n] to LDS ONCE (as [n][c] bf16),
// ---- one barrier, then 80 MFMAs flat (no in-loop syncs at all).
__global__ __launch_bounds__(256) void proj_kernel(
    const float* __restrict__ x, const __hip_bfloat16* __restrict__ W16,
    const float* __restrict__ bq, const float* __restrict__ bk,
    const float* __restrict__ bv, __hip_bfloat16* __restrict__ q,
    __hip_bfloat16* __restrict__ kT, __hip_bfloat16* __restrict__ v) {
  __shared__ __hip_bfloat16 Xs[32 * XS2];   // 16896 B
  const int t = threadIdx.x;
  const int b = blockIdx.y, n0 = blockIdx.x * 32;
  const int w = __builtin_amdgcn_readfirstlane(t >> 6);   // wave: o rows [w*80, w*80+80)
  const int ln = t & 15, quad = (t & 63) >> 4;
  const int sn = t & 31, scg = t >> 5;   // staging: n lane, c-group (8 groups of 8)

  const float* xsrc = x + (size_t)b * NC * NN + n0 + sn;
  float xr[4][8];
#pragma unroll
  for (int g = 0; g < 4; ++g)
#pragma unroll
    for (int i = 0; i < 8; ++i)
      xr[g][i] = xsrc[(size_t)(g * 64 + scg * 8 + i) * NN];
#pragma unroll
  for (int g = 0; g < 4; ++g) {
    uint4 pw;
    pw.x = pk2bf(xr[g][0], xr[g][1]);
    pw.y = pk2bf(xr[g][2], xr[g][3]);
    pw.z = pk2bf(xr[g][4], xr[g][5]);
    pw.w = pk2bf(xr[g][6], xr[g][7]);
    *(uint4*)&Xs[sn * XS2 + g * 64 + scg * 8] = pw;
  }
  __syncthreads();

  f32x4 zero4 = {0.f, 0.f, 0.f, 0.f};
  f32x4 acc[5][2];
#pragma unroll
  for (int i = 0; i < 5; ++i)
#pragma unroll
    for (int j = 0; j < 2; ++j) acc[i][j] = zero4;

#pragma unroll
  for (int k0 = 0; k0 < NC; k0 += 32) {
    short8 af[5], bfr[2];
#pragma unroll
    for (int ot = 0; ot < 5; ++ot)
      af[ot] = *(const short8*)(W16 + (size_t)(w * 80 + ot * 16 + ln) * NC + k0 + quad * 8);
#pragma unroll
    for (int nt = 0; nt < 2; ++nt)
      bfr[nt] = *(const short8*)&Xs[(nt * 16 + ln) * XS2 + k0 + quad * 8];
#pragma unroll
    for (int ot = 0; ot < 5; ++ot)
#pragma unroll
      for (int nt = 0; nt < 2; ++nt)
        acc[ot][nt] = MFMA16(af[ot], bfr[nt], acc[ot][nt]);
  }

#pragma unroll
  for (int ot = 0; ot < 5; ++ot) {
    const int gbase = w * 80 + ot * 16;    // wave-uniform
    if (gbase < 32) {
#pragma unroll
      for (int nt = 0; nt < 2; ++nt)
#pragma unroll
        for (int r = 0; r < 4; ++r) {
          const int row = gbase + quad * 4 + r;
          q[((size_t)b * NN + n0 + nt * 16 + ln) * DQK + row] =
              __hip_bfloat16(acc[ot][nt][r] + bq[row]);
        }
    } else if (gbase < 64) {
#pragma unroll
      for (int nt = 0; nt < 2; ++nt)
#pragma unroll
        for (int r = 0; r < 4; ++r) {
          const int row = gbase - 32 + quad * 4 + r;
          kT[((size_t)b * NN + n0 + nt * 16 + ln) * DQK + row] =
              __hip_bfloat16(acc[ot][nt][r] + bk[row]);
        }
    } else {
#pragma unroll
      for (int nt = 0; nt < 2; ++nt)
#pragma unroll
        for (int r = 0; r < 4; ++r) {
          const int c = gbase - 64 + quad * 4 + r;
          v[((size_t)b * NC + c) * NN + n0 + nt * 16 + ln] =
              __hip_bfloat16(acc[ot][nt][r] + bv[c]);
        }
    }
  }
}

// ---- wave-specialized flash with LDS-staged K and V via global_load_lds.
// K/V tiles land in LDS as XOR-swizzled layouts (source pre-swizzle, linear
// dest); fragment reads are bank-clean ds_read_b128. ~2.7x fewer VMEM
// transactions than direct fragment gathers. __syncthreads per iter drains
// stages issued a full iteration earlier (latency covered).
__global__ __launch_bounds__(512, 2) void flash_kernel(
    const __hip_bfloat16* __restrict__ q, const __hip_bfloat16* __restrict__ kt,
    const __hip_bfloat16* __restrict__ v, const float* __restrict__ x,
    const float* __restrict__ gamma, float* __restrict__ out) {
  __shared__ __align__(16) __hip_bfloat16 Ks[2][JT * DQK];    // 8 KB
  __shared__ __align__(16) __hip_bfloat16 Vs[2][NC * JT];     // 64 KB
  __shared__ __align__(16) __hip_bfloat16 Ps[2][MT * JT];     // 16 KB
  __shared__ float lrow[MT];

  const int t  = threadIdx.x;
  const int bi = blockIdx.x;
  // XCD swizzle: XCD pair {2b,2b+1} serves batch b -> K/V slices stay L2-local
  const int b  = (bi & 7) >> 1;
  const int m0 = (((bi & 1) * 32) + (bi >> 3)) * MT;

  const int w    = __builtin_amdgcn_readfirstlane(t >> 6);   // 0..7
  const int l    = t & 63;
  const int ln   = t & 15;
  const int quad = (t & 63) >> 4;

  const __hip_bfloat16* kb_base = kt + (size_t)b * NN * DQK;
  const __hip_bfloat16* v_base  = v + (size_t)b * NC * NN;

  // V stage: wave w covers granules g = w*4+k (8 c-rows x 64 j each).
  // LDS byte (g*1024 + l*16): c = g*8 + (l>>3), chunk x = l&7 holds
  // j-chunk (x ^ (c&7)) -> src = V[c][j0 + (x^(c&7))*8].
  size_t voff[4];
#pragma unroll
  for (int k = 0; k < 4; ++k) {
    const int g = w * 4 + k;
    const int c = g * 8 + (l >> 3);
    voff[k] = (size_t)c * NN + (((l & 7) ^ ((l >> 3) & 7)) * 8);
  }
  // K stage (producers only): wave w covers granule w (16 j-rows x 32 d).
  // LDS byte (w*1024 + l*16): r = w*16 + (l>>2), chunk x = l&3 holds
  // d-chunk (x ^ (r&3)).
  const size_t koff = (size_t)(w * 16 + (l >> 2)) * DQK +
                      (((l & 3) ^ ((l >> 2) & 3)) * 8);

  // prologue: stage K(0)
  if (w < 4) gl16(kb_base + koff, &Ks[0][w * 512]);
  __syncthreads();

  if (w < 4) {
    // ------- producer: m = m0 + w*16 + ln (lane-local row via swapped QK) -------
    const short8 qa =
        *(const short8*)(q + ((size_t)b * NN + m0 + w * 16 + ln) * DQK + quad * 8);
    float lreg = 0.f;
    const f32x4 zero4 = {0.f, 0.f, 0.f, 0.f};
    const int m = w * 16 + ln;

    for (int it = 0; it < NIT; ++it) {
      // stage V(it) and K(it+1) (issue-early; drained by this iter's barrier)
#pragma unroll
      for (int k = 0; k < 4; ++k)
        gl16(v_base + voff[k] + (size_t)it * JT, &Vs[it & 1][(w * 4 + k) * 512]);
      if (it + 1 < NIT)
        gl16(kb_base + koff + (size_t)(it + 1) * JT * DQK, &Ks[(it + 1) & 1][w * 512]);

      // K fragments from swizzled LDS
      short8 kb[4];
#pragma unroll
      for (int jt = 0; jt < 4; ++jt)
        kb[jt] = *(const short8*)&Ks[it & 1][(jt * 16 + ln) * DQK +
                                            ((quad ^ (ln & 3)) * 8)];
      // S^T strip: mfma(K, Q) -> lane holds S[m=ln][j = jt*16 + quad*4 + r]
      f32x4 st[4];
      __builtin_amdgcn_s_setprio(1);
#pragma unroll
      for (int jt = 0; jt < 4; ++jt) st[jt] = MFMA16(kb[jt], qa, zero4);
      __builtin_amdgcn_s_setprio(0);

      // P = exp(S); packed b64 swizzled writes
      char* pbase = (char*)&Ps[it & 1][0] + m * (JT * 2);
#pragma unroll
      for (int jt = 0; jt < 4; ++jt) {
        const float e0 = __expf(st[jt][0]), e1 = __expf(st[jt][1]);
        const float e2 = __expf(st[jt][2]), e3 = __expf(st[jt][3]);
        lreg += (e0 + e1) + (e2 + e3);
        *(uint2*)(pbase + ((jt * 32 + quad * 8) ^ ((m & 7) << 4))) =
            make_uint2(pk2bf(e0, e1), pk2bf(e2, e3));
      }
      __syncthreads();
    }
    // reduce l over the 4 quads (disjoint j subsets per quad)
    lreg += __shfl_xor(lreg, 16);
    lreg += __shfl_xor(lreg, 32);
    if (quad == 0) lrow[w * 16 + ln] = lreg;
    __syncthreads();
  } else {
    // ------- consumer: channels [c0, c0+64), one iter behind -------
    const int c0 = (w - 4) * 64;
    const f32x4 zero4 = {0.f, 0.f, 0.f, 0.f};
    f32x4 acc[4][4];   // rows c = c0+ct*16+quad*4+r, cols m = mt*16+ln
#pragma unroll
    for (int ct = 0; ct < 4; ++ct)
#pragma unroll
      for (int mt = 0; mt < 4; ++mt) acc[ct][mt] = zero4;

    for (int it = 0; it < NIT; ++it) {
      // stage V(it)
#pragma unroll
      for (int k = 0; k < 4; ++k)
        gl16(v_base + voff[k] + (size_t)it * JT, &Vs[it & 1][(w * 4 + k) * 512]);

      if (it > 0) {
        const int pbuf = (it - 1) & 1;
        const char* pbase = (const char*)&Ps[pbuf][0];
        // V fragments from swizzled LDS: va[ct][ks], j-chunk jx = ks*4+quad
        short8 va[4][2];
#pragma unroll
        for (int ct = 0; ct < 4; ++ct)
#pragma unroll
          for (int ks = 0; ks < 2; ++ks)
            va[ct][ks] = *(const short8*)&Vs[pbuf][
                (c0 + ct * 16 + ln) * JT + (((ks * 4 + quad) ^ (ln & 7)) * 8)];
#pragma unroll
        for (int ks = 0; ks < 2; ++ks) {
          short8 pb[4];
#pragma unroll
          for (int mt = 0; mt < 4; ++mt)
            pb[mt] = *(const short8*)(pbase + (mt * 16 + ln) * (JT * 2) +
                                      ((ks * 64 + quad * 16) ^ ((ln & 7) << 4)));
          __builtin_amdgcn_s_setprio(1);
#pragma unroll
          for (int ct = 0; ct < 4; ++ct)
#pragma unroll
            for (int mt = 0; mt < 4; ++mt)
              acc[ct][mt] = MFMA16(va[ct][ks], pb[mt], acc[ct][mt]);
          __builtin_amdgcn_s_setprio(0);
        }
      }
      __syncthreads();
    }

    // final PV for tile NIT-1 (staged/written during iter NIT-1)
    {
      const int pbuf = (NIT - 1) & 1;
      const char* pbase = (const char*)&Ps[pbuf][0];
      short8 va[4][2];
#pragma unroll
      for (int ct = 0; ct < 4; ++ct)
#pragma unroll
        for (int ks = 0; ks < 2; ++ks)
          va[ct][ks] = *(const short8*)&Vs[pbuf][
              (c0 + ct * 16 + ln) * JT + (((ks * 4 + quad) ^ (ln & 7)) * 8)];
#pragma unroll
      for (int ks = 0; ks < 2; ++ks) {
        short8 pb[4];
#pragma unroll
        for (int mt = 0; mt < 4; ++mt)
          pb[mt] = *(const short8*)(pbase + (mt * 16 + ln) * (JT * 2) +
                                    ((ks * 64 + quad * 16) ^ ((ln & 7) << 4)));
        __builtin_amdgcn_s_setprio(1);
#pragma unroll
        for (int ct = 0; ct < 4; ++ct)
#pragma unroll
          for (int mt = 0; mt < 4; ++mt)
            acc[ct][mt] = MFMA16(va[ct][ks], pb[mt], acc[ct][mt]);
        __builtin_amdgcn_s_setprio(0);
      }
    }
    __syncthreads();   // lrow visible

    // epilogue: out[b][c][m] = gamma*(O'/l) + x
    const float g0 = gamma[0];
    float li[4];
#pragma unroll
    for (int mt = 0; mt < 4; ++mt) li[mt] = 1.f / lrow[mt * 16 + ln];
#pragma unroll
    for (int ct = 0; ct < 4; ++ct)
#pragma unroll
      for (int r = 0; r < 4; ++r) {
        const int c = c0 + ct * 16 + quad * 4 + r;
        const float* xr = x + ((size_t)b * NC + c) * NN + m0;
        float* orow = out + ((size_t)b * NC + c) * NN + m0;
#pragma unroll
        for (int mt = 0; mt < 4; ++mt) {
          const int m = mt * 16 + ln;
          orow[m] = g0 * (acc[ct][mt][r] * li[mt]) + xr[m];
        }
      }
  }
}

extern "C" void kernel_launch(void* const* d_in, const int* in_sizes, int n_in,
                              void* d_out, int out_size, void* d_ws, size_t ws_size,
                              hipStream_t stream) {
  const float* x     = (const float*)d_in[0];
  const float* Wq    = (const float*)d_in[1];
  const float* bq    = (const float*)d_in[2];
  const float* Wk    = (const float*)d_in[3];
  const float* bk    = (const float*)d_in[4];
  const float* Wv    = (const float*)d_in[5];
  const float* bv    = (const float*)d_in[6];
  const float* gamma = (const float*)d_in[7];
  float* out = (float*)d_out;

  char* wsp = (char*)d_ws;
  __hip_bfloat16* W16 = (__hip_bfloat16*)wsp;  wsp += (size_t)320 * NC * 2;
  __hip_bfloat16* q   = (__hip_bfloat16*)wsp;  wsp += (size_t)NB * NN * DQK * 2;
  __hip_bfloat16* kT  = (__hip_bfloat16*)wsp;  wsp += (size_t)NB * NN * DQK * 2;
  __hip_bfloat16* v   = (__hip_bfloat16*)wsp;  // + 8.4 MB => ~10.6 MB total

  wcvt_kernel<<<dim3(80), dim3(256), 0, stream>>>(Wq, Wk, Wv, W16);
  proj_kernel<<<dim3(NN / 32, NB), dim3(256), 0, stream>>>(x, W16, bq, bk, bv, q, kT, v);
  flash_kernel<<<dim3(NB * NN / MT), dim3(512), 0, stream>>>(q, kT, v, x, gamma, out);
}